// Round 5
// baseline (6692.741 us; speedup 1.0000x reference)
//
#include <hip/hip_runtime.h>
#include <hip/hip_bf16.h>

#define DEV __device__ __forceinline__

namespace {

constexpr int ROWS = 64 * 4096;        // B*T
constexpr int NE   = ROWS * 64;        // B*T*F
constexpr int CHUNK = 512;
constexpr int NCHUNK = 4096 / CHUNK;   // 8
constexpr int NH1 = 48, NH2 = 48, NH3 = 32;

constexpr size_t GXCH = (size_t)64 * CHUNK * 384;   // elems per gx chunk buf
constexpr size_t RCH  = (size_t)64 * CHUNK * 128;   // elems per z/r1/r2 chunk buf

// workspace layout (bytes), total ~185.1 MB
constexpr size_t OFF_XC  = 0;            // bf16 NE          33,554,432
constexpr size_t OFF_MC  = 33554432;     // u8 NE            16,777,216
constexpr size_t OFF_WC  = 50331648;     // fp32 weights
constexpr size_t OFF_ACC = 50862080;     // 4 KB acc/flags
constexpr size_t OFF_H2  = 50866176;     // f16 NE           33,554,432
constexpr size_t OFF_GX  = 84420608;     // f16 2*GXCH       50,331,648
constexpr size_t OFF_ZR  = 134752256;    // f16 2*RCH        16,777,216
constexpr size_t OFF_R1  = 151529472;    // f16 2*RCH
constexpr size_t OFF_R2  = 168306688;    // f16 2*RCH
constexpr size_t OFF_HST = 185083904;    // fp32 64*128

DEV float rlane(float v, int l) {
    return __int_as_float(__builtin_amdgcn_readlane(__float_as_int(v), l));
}
DEV unsigned int rlu(unsigned int v, int l) {
    return (unsigned int)__builtin_amdgcn_readlane((int)v, l);
}
DEV float bf2f(unsigned short u) { return __uint_as_float(((unsigned int)u) << 16); }
DEV unsigned short f2bf(float f) {
    unsigned int u = __float_as_uint(f);
    unsigned int r = (u + 0x7FFFu + ((u >> 16) & 1u)) >> 16;
    return (unsigned short)r;
}
DEV float gelu_f(float v) { return 0.5f * v * (1.0f + erff(v * 0.70710678118654752f)); }
DEV float sigm_f(float x) { return 1.0f / (1.0f + __expf(-x)); }
DEV float tanh_f(float x) { float t = __expf(2.0f * x); return 1.0f - 2.0f / (t + 1.0f); }

typedef _Float16 half2v __attribute__((ext_vector_type(2)));

DEV float dot2(half2v a, half2v b, float c) {
#if __has_builtin(__builtin_amdgcn_fdot2)
    return __builtin_amdgcn_fdot2(a, b, c, false);
#else
    return c + (float)a.x * (float)b.x + (float)a.y * (float)b.y;
#endif
}
DEV unsigned short f2h_bits(float f) {
    return __builtin_bit_cast(unsigned short, (_Float16)f);
}
DEV float h2f_bits(unsigned short u) {
    return (float)__builtin_bit_cast(_Float16, u);
}
DEV half2v u2h2(unsigned int p) { return __builtin_bit_cast(half2v, p); }
// LDS-only barrier: skips the vmcnt(0) drain __syncthreads would emit.
DEV void bar_lds() {
    asm volatile("s_waitcnt lgkmcnt(0)\n\ts_barrier" ::: "memory");
}

} // namespace

// ---------------- dtype probe (memory-safe) ----------------
__global__ __launch_bounds__(256) void k_probe(const unsigned short* __restrict__ xh,
    const unsigned char* __restrict__ mb, int* __restrict__ cnt)
{
    const int g = blockIdx.x * 256 + threadIdx.x;
    int hit = 0;
    for (int i = g; i < (1 << 20); i += (1 << 16)) {
        int tb = (xh[i] >> 8) & 0x7F;
        hit += (tb >= 0x3C && tb <= 0x40) ? 1 : 0;
    }
    int a = 0, b = 0, c = 0, d = 0;
    for (int i = g; i < (1 << 24); i += (1 << 16)) {
        unsigned char v = mb[i];
        int r = i & 3;
        a += (v == 1    && r == 0) ? 1 : 0;
        b += (v == 1    && r != 0) ? 1 : 0;
        c += (v == 0x80 && r == 0) ? 1 : 0;
        d += (v == 0x80 && r == 2) ? 1 : 0;
    }
    __shared__ int sm[256];
    int vals[5] = {hit, a, b, c, d};
#pragma unroll
    for (int k = 0; k < 5; ++k) {
        sm[threadIdx.x] = vals[k];
        __syncthreads();
        for (int s = 128; s > 0; s >>= 1) {
            if (threadIdx.x < s) sm[threadIdx.x] += sm[threadIdx.x + s];
            __syncthreads();
        }
        if (threadIdx.x == 0) atomicAdd(cnt + k, sm[0]);
        __syncthreads();
    }
}

__global__ void k_classify(const int* __restrict__ cnt, int* __restrict__ flags)
{
    flags[0] = (cnt[0] > 786432) ? 0 : 1;
    int fm;
    if (cnt[2] > 0) fm = 0;
    else if (cnt[1] > 0) fm = 1;
    else if (cnt[3] > 0) fm = 2;
    else if (cnt[4] > 0) fm = 3;
    else fm = 0;
    flags[1] = fm;
}

// ---------------- canonicalize x (bf16) + mask (u8) ----------------
__global__ __launch_bounds__(256) void k_canon_x(const void* __restrict__ x,
    const void* __restrict__ mask, unsigned short* __restrict__ xc,
    unsigned char* __restrict__ mc, const int* __restrict__ flags)
{
    const int fF = flags[0], fM = flags[1];
    for (int i = blockIdx.x * 256 + threadIdx.x; i < NE; i += gridDim.x * 256) {
        unsigned short h;
        if (fF == 0) h = ((const unsigned short*)x)[i];
        else         h = f2bf(((const float*)x)[i]);
        xc[i] = h;
        unsigned char m;
        if (fM == 0)      m = (((const unsigned char*)mask)[i]  != 0) ? 1 : 0;
        else if (fM == 1) m = (((const int*)mask)[i]            != 0) ? 1 : 0;
        else if (fM == 2) m = (((const unsigned short*)mask)[i] != 0) ? 1 : 0;
        else              m = (((const unsigned int*)mask)[i]   != 0) ? 1 : 0;
        mc[i] = m;
    }
}

// ---------------- canonicalize weights to fp32 ----------------
__global__ __launch_bounds__(256) void k_canon_w(
    const void* p0, const void* p1, const void* p2, const void* p3,
    const void* p4, const void* p5, const void* p6, const void* p7,
    const void* p8, const void* p9, const void* p10, const void* p11,
    const void* p12, const void* p13, float* __restrict__ wc,
    const int* __restrict__ flags)
{
    const int fF = flags[0];
    const void* p; int off, n;
    switch (blockIdx.x) {
        case 0:  p = p0;  off = 0;      n = 4096;  break;  // stem_w
        case 1:  p = p1;  off = 4096;   n = 64;    break;  // stem_b
        case 2:  p = p2;  off = 4160;   n = 12288; break;  // conv_w
        case 3:  p = p3;  off = 16448;  n = 64;    break;  // conv_b
        case 4:  p = p4;  off = 16512;  n = 24576; break;  // w_ih
        case 5:  p = p5;  off = 41088;  n = 49152; break;  // w_hh
        case 6:  p = p6;  off = 90240;  n = 384;   break;  // b_ih
        case 7:  p = p7;  off = 90624;  n = 384;   break;  // b_hh
        case 8:  p = p8;  off = 91008;  n = 16384; break;  // h1_w
        case 9:  p = p9;  off = 107392; n = 128;   break;  // h1_b
        case 10: p = p10; off = 107520; n = 16384; break;  // h2_w
        case 11: p = p11; off = 123904; n = 128;   break;  // h2_b
        case 12: p = p12; off = 124032; n = 8192;  break;  // h3_w
        default: p = p13; off = 132224; n = 64;    break;  // h3_b
    }
    for (int i = threadIdx.x; i < n; i += 256) {
        float v = (fF == 0) ? bf2f(((const unsigned short*)p)[i]) : ((const float*)p)[i];
        wc[off + i] = v;
    }
}

// ---------------- std over features + mask count ----------------
__global__ __launch_bounds__(256) void k_std(const unsigned short* __restrict__ xc,
    const unsigned char* __restrict__ mc, double* __restrict__ acc)
{
    const int tid = threadIdx.x, f = tid & 63, slot = tid >> 6;
    float s = 0.f, sq = 0.f; int cnt = 0;
    for (int row = blockIdx.x * 4 + slot; row < ROWS; row += gridDim.x * 4) {
        const size_t base = (size_t)row * 64 + f;
        float v = bf2f(xc[base]);
        s += v; sq += v * v;
        cnt += mc[base];
    }
    __shared__ float ls[256], lq[256];
    __shared__ int lc[256];
    ls[tid] = s; lq[tid] = sq; lc[tid] = cnt;
    __syncthreads();
    if (tid < 64) {
        float S = ls[tid] + ls[tid + 64] + ls[tid + 128] + ls[tid + 192];
        float Q = lq[tid] + lq[tid + 64] + lq[tid + 128] + lq[tid + 192];
        atomicAdd(acc + tid, (double)S);
        atomicAdd(acc + 64 + tid, (double)Q);
    }
    if (tid == 0) {
        int tot = 0;
        for (int i = 0; i < 256; ++i) tot += lc[i];
        atomicAdd(acc + 128, (double)tot);
    }
}

__global__ void k_scale(const double* __restrict__ acc, float* __restrict__ inv2)
{
    int f = threadIdx.x;
    const double N = (double)ROWS;
    double sum = acc[f], sq = acc[64 + f];
    double var = (sq - sum * sum / N) / (N - 1.0);
    double sd = sqrt(var) + 1e-8;
    inv2[f] = (float)(1.0 / (sd * sd));
}

// ---------------- fused stem + conv (halo strip in LDS), h2 f16 out --------
__global__ __launch_bounds__(768) void k_stemconv(const unsigned short* __restrict__ xc,
    const unsigned char* __restrict__ mc, const float* __restrict__ sw,
    const float* __restrict__ sb, const float* __restrict__ cw,
    const float* __restrict__ cb, unsigned short* __restrict__ h2)
{
    __shared__ float h1s[66][64];
    __shared__ float parts[3][4][64];
    const int tid = threadIdx.x, lane = tid & 63, wav = tid >> 6;
    const int b = blockIdx.x >> 6, strip = blockIdx.x & 63, t0 = strip * 64;

    float wv[64];
#pragma unroll
    for (int d = 0; d < 64; ++d) wv[d] = sw[d * 64 + lane];
    const float sbias = sb[lane];
    for (int rr = wav; rr < 66; rr += 12) {
        const int tr = t0 + rr - 1;
        float val = 0.f;
        if (tr >= 0 && tr < 4096) {
            const size_t base = ((size_t)b * 4096 + tr) * 64;
            float xv = bf2f(xc[base + lane]);
            if (mc[base + lane]) xv = 0.f;
            float a0 = 0.f, a1 = 0.f, a2 = 0.f, a3 = 0.f;
#pragma unroll
            for (int d = 0; d < 64; d += 4) {
                a0 += rlane(xv, d    ) * wv[d    ];
                a1 += rlane(xv, d + 1) * wv[d + 1];
                a2 += rlane(xv, d + 2) * wv[d + 2];
                a3 += rlane(xv, d + 3) * wv[d + 3];
            }
            val = gelu_f(((a0 + a1) + (a2 + a3)) + sbias);
        }
        h1s[rr][lane] = val;
    }
    __syncthreads();

    const int k = wav >> 2, j = wav & 3;
    float cwv[64];
#pragma unroll
    for (int i = 0; i < 64; ++i) cwv[i] = cw[lane * 192 + i * 3 + k];
    const float cbias = cb[lane];
    for (int it = 0; it < 16; ++it) {
        const int row = it * 4 + j;
        float hv = h1s[row + k][lane];
        float a0 = 0.f, a1 = 0.f, a2 = 0.f, a3 = 0.f;
#pragma unroll
        for (int i = 0; i < 64; i += 4) {
            a0 += rlane(hv, i    ) * cwv[i    ];
            a1 += rlane(hv, i + 1) * cwv[i + 1];
            a2 += rlane(hv, i + 2) * cwv[i + 2];
            a3 += rlane(hv, i + 3) * cwv[i + 3];
        }
        parts[k][j][lane] = (a0 + a1) + (a2 + a3);
        __syncthreads();
        if (tid < 256) {
            const int jj = tid >> 6;
            const int row2 = it * 4 + jj;
            float v = parts[0][jj][lane] + parts[1][jj][lane] + parts[2][jj][lane] + cbias;
            h2[((size_t)b * 4096 + t0 + row2) * 64 + lane] = f2h_bits(gelu_f(v));
        }
        __syncthreads();
    }
}

// ---------------- gx for chunk 0 (standalone) ----------------
__global__ __launch_bounds__(384) void k_gx0(const unsigned short* __restrict__ h2,
    const float* __restrict__ wih, const float* __restrict__ bih,
    const float* __restrict__ bhh, unsigned short* __restrict__ gx0)
{
    const int tid = threadIdx.x, lane = tid & 63, wav = tid >> 6; // 6 waves
    const int col = wav * 64 + lane;
    half2v wg[32];
#pragma unroll
    for (int i = 0; i < 32; ++i)
        wg[i] = half2v{(_Float16)wih[(size_t)col * 64 + 2 * i],
                       (_Float16)wih[(size_t)col * 64 + 2 * i + 1]};
    const float gb = bih[col] + (col < 256 ? bhh[col] : 0.f);
    const unsigned int* h232 = (const unsigned int*)h2;
    const int b = blockIdx.x;
    const size_t hb = (size_t)b * 4096 * 32;
    unsigned int hw = h232[hb + (lane & 31)];
    for (int t = 0; t < CHUNK; ++t) {
        unsigned int hwn = (t + 1 < CHUNK) ? h232[hb + (size_t)(t + 1) * 32 + (lane & 31)] : 0u;
        float s = 0.f;
#pragma unroll
        for (int i = 0; i < 32; ++i)
            s = dot2(u2h2(rlu(hw, i)), wg[i], s);
        gx0[((size_t)b * CHUNK + t) * 384 + col] = f2h_bits(s + gb);
        hw = hwn;
    }
}

// ---------------- head helpers (f16-pair dot2, weights 64 VGPR) ------------
DEV void head_layer(const unsigned short* __restrict__ in,
                    unsigned short* __restrict__ out,
                    const float* __restrict__ w, const float* __restrict__ bias,
                    int hb, int nb)
{
    const int tid = threadIdx.x, lane = tid & 63, wav = tid >> 6;
    const int tm = wav >> 1, cs = wav & 1;
    const int col = cs * 64 + lane;
    half2v wv[64];
#pragma unroll
    for (int i = 0; i < 64; ++i)
        wv[i] = half2v{(_Float16)w[(size_t)(2 * i) * 128 + col],
                       (_Float16)w[(size_t)(2 * i + 1) * 128 + col]};
    const float bb = bias[col];
    for (int r = hb * 6 + tm; r < 64 * CHUNK; r += nb * 6) {
        const unsigned int* ir = (const unsigned int*)(in + (size_t)r * 128);
        unsigned int zw = ir[lane];       // pairs (z[2lane], z[2lane+1])
        float a0 = 0.f, a1 = 0.f;
#pragma unroll
        for (int i = 0; i < 64; i += 2) {
            a0 = dot2(u2h2(rlu(zw, i)),     wv[i],     a0);
            a1 = dot2(u2h2(rlu(zw, i + 1)), wv[i + 1], a1);
        }
        out[(size_t)r * 128 + col] = f2h_bits(gelu_f(a0 + a1 + bb));
    }
}

DEV void head3_layer(const unsigned short* __restrict__ in,
                     const float* __restrict__ w, const float* __restrict__ bias,
                     const unsigned short* __restrict__ xc,
                     const unsigned char* __restrict__ mc,
                     const float* __restrict__ inv2, double* __restrict__ lossacc,
                     int hb, int nb, int hc)
{
    const int tid = threadIdx.x, lane = tid & 63, wav = tid >> 6;
    half2v wv[64];
#pragma unroll
    for (int i = 0; i < 64; ++i)
        wv[i] = half2v{(_Float16)w[(size_t)(2 * i) * 64 + lane],
                       (_Float16)w[(size_t)(2 * i + 1) * 64 + lane]};
    const float bb = bias[lane];
    const float iv = inv2[lane];
    float accf = 0.f; double acc = 0.0; int spill = 0;
    for (int r = hb * 12 + wav; r < 64 * CHUNK; r += nb * 12) {
        const unsigned int* ir = (const unsigned int*)(in + (size_t)r * 128);
        unsigned int zw = ir[lane];
        float a0 = 0.f, a1 = 0.f;
#pragma unroll
        for (int i = 0; i < 64; i += 2) {
            a0 = dot2(u2h2(rlu(zw, i)),     wv[i],     a0);
            a1 = dot2(u2h2(rlu(zw, i + 1)), wv[i + 1], a1);
        }
        float xr = a0 + a1 + bb;
        const int bidx = r >> 9, tl = r & (CHUNK - 1);
        const int t = hc * CHUNK + tl;
        const size_t xb = ((size_t)bidx * 4096 + t) * 64 + lane;
        float dd = xr - bf2f(xc[xb]);
        accf += mc[xb] ? dd * dd * iv : 0.f;
        if (++spill == 64) { acc += (double)accf; accf = 0.f; spill = 0; }
    }
    acc += (double)accf;
    __shared__ double red[768];
    red[tid] = acc;
    __syncthreads();
    if (tid < 256) red[tid] += red[tid + 256] + red[tid + 512];
    __syncthreads();
    for (int s = 128; s > 0; s >>= 1) {
        if (tid < s) red[tid] += red[tid + s];
        __syncthreads();
    }
    if (tid == 0) atomicAdd(lossacc, red[0]);
}

// ---------------- mega kernel: GRU(c) + gx(c+1) in-block + pipelined heads --
// GRU blocks (blockIdx < ngru, one per batch): 12 waves =
//   waves 0-3: matvec (ks = wav&1 K-half, dh = wav>>1 d-half), f16 dot2
//   waves 4-5: gates (d = tid-256), scalar 2-step gx prefetch
//   waves 6-11: gx producer for chunk c+1, one 64-col unit per step
// All 12 waves run the same t-loop with 2 lgkm-only barriers per step.
// Head blocks: head1(c-1) z->r1, head2(c-2) r1->r2, head3(c-3) r2->loss.
__global__ __launch_bounds__(768) void k_mega(int ngru, int c,
    unsigned short* __restrict__ gxring, const unsigned short* __restrict__ h2,
    const float* __restrict__ wih, const float* __restrict__ bih,
    const float* __restrict__ whh, const float* __restrict__ bhh,
    unsigned short* __restrict__ zring, unsigned short* __restrict__ r1ring,
    unsigned short* __restrict__ r2ring, float* __restrict__ hstate,
    const float* __restrict__ h1w, const float* __restrict__ h1b,
    const float* __restrict__ h2w, const float* __restrict__ h2b,
    const float* __restrict__ h3w, const float* __restrict__ h3b,
    const unsigned short* __restrict__ xc, const unsigned char* __restrict__ mc,
    const float* __restrict__ inv2, double* __restrict__ lossacc)
{
    const int tid = threadIdx.x, lane = tid & 63, wav = tid >> 6;

    if ((int)blockIdx.x < ngru) {
        __shared__ float part[2][3][132];
        __shared__ unsigned int hpk[64];   // h as packed f16 pairs
        const int b = blockIdx.x;
        const unsigned short* gxs = gxring + (size_t)(c & 1) * GXCH + (size_t)b * CHUNK * 384;
        unsigned short* gxd = gxring + (size_t)((c + 1) & 1) * GXCH + (size_t)b * CHUNK * 384;
        unsigned short* zc  = zring  + (size_t)(c & 1) * RCH  + (size_t)b * CHUNK * 128;
        const bool do_gx = (c + 1) < NCHUNK;

        // --- role setup ---
        half2v wr[32], wz[32], wn[32];                 // matvec
        int kb = 0, dmv = 0, ksu = 0;
        unsigned short cr = 0, cz = 0, cn = 0, nr = 0, nz = 0, nn = 0; // gates
        float hown = 0.f, bhn = 0.f;
        int dg = 0;
        half2v wg[32]; float gbias = 0.f;              // gx
        unsigned int hw2 = 0;
        const unsigned int* h2w32 = (const unsigned int*)h2;
        size_t h2base = 0; int gcol = 0;

        if (wav < 4) {
            ksu = wav & 1;
            dmv = (wav >> 1) * 64 + lane;
            kb = __builtin_amdgcn_readfirstlane(ksu * 32);
#pragma unroll
            for (int i = 0; i < 32; ++i) {
                const int k0 = ksu * 64 + 2 * i;
                wr[i] = half2v{(_Float16)whh[(size_t)dmv * 128 + k0],
                               (_Float16)whh[(size_t)dmv * 128 + k0 + 1]};
                wz[i] = half2v{(_Float16)whh[(size_t)(128 + dmv) * 128 + k0],
                               (_Float16)whh[(size_t)(128 + dmv) * 128 + k0 + 1]};
                wn[i] = half2v{(_Float16)whh[(size_t)(256 + dmv) * 128 + k0],
                               (_Float16)whh[(size_t)(256 + dmv) * 128 + k0 + 1]};
            }
        } else if (wav < 6) {
            dg = tid - 256;
            bhn = bhh[256 + dg];
            float h0 = (c == 0) ? 0.f : hstate[b * 128 + dg];
            hown = h0;
            ((unsigned short*)hpk)[dg] = f2h_bits(h0);
            cr = gxs[dg];            cz = gxs[128 + dg];            cn = gxs[256 + dg];
            nr = gxs[384 + dg];      nz = gxs[384 + 128 + dg];      nn = gxs[384 + 256 + dg];
        } else {
            const int cg = wav - 6;
            gcol = cg * 64 + lane;
#pragma unroll
            for (int i = 0; i < 32; ++i)
                wg[i] = half2v{(_Float16)wih[(size_t)gcol * 64 + 2 * i],
                               (_Float16)wih[(size_t)gcol * 64 + 2 * i + 1]};
            gbias = bih[gcol] + (gcol < 256 ? bhh[gcol] : 0.f);
            if (do_gx) {
                h2base = ((size_t)b * 4096 + (size_t)(c + 1) * CHUNK) * 32;
                hw2 = h2w32[h2base + (lane & 31)];
            }
        }
        __syncthreads();

        for (int t = 0; t < CHUNK; ++t) {
            // ---------- phase A ----------
            if (wav < 4) {
                const unsigned int hw = hpk[lane];
                float sr = 0.f, sz = 0.f, sn = 0.f;
#pragma unroll
                for (int i = 0; i < 32; ++i) {
                    const half2v hp = u2h2(rlu(hw, kb + i));
                    sr = dot2(hp, wr[i], sr);
                    sz = dot2(hp, wz[i], sz);
                    sn = dot2(hp, wn[i], sn);
                }
                part[ksu][0][dmv] = sr;
                part[ksu][1][dmv] = sz;
                part[ksu][2][dmv] = sn;
            } else if (wav >= 6 && do_gx) {
                unsigned int hw2n = 0;
                if (t + 1 < CHUNK) hw2n = h2w32[h2base + (size_t)(t + 1) * 32 + (lane & 31)];
                float s = 0.f;
#pragma unroll
                for (int i = 0; i < 32; ++i)
                    s = dot2(u2h2(rlu(hw2, i)), wg[i], s);
                gxd[(size_t)t * 384 + gcol] = f2h_bits(s + gbias);
                hw2 = hw2n;
            }
            bar_lds();
            // ---------- phase B ----------
            if (wav == 4 || wav == 5) {
                const float gr  = part[0][0][dg] + part[1][0][dg] + h2f_bits(cr);
                const float gz  = part[0][1][dg] + part[1][1][dg] + h2f_bits(cz);
                const float gnh = part[0][2][dg] + part[1][2][dg] + bhn;
                const float r  = sigm_f(gr);
                const float zg = sigm_f(gz);
                const float n  = tanh_f(h2f_bits(cn) + r * gnh);
                hown = n + zg * (hown - n);
                ((unsigned short*)hpk)[dg] = f2h_bits(hown);
                zc[(size_t)t * 128 + dg] = f2h_bits(hown);
                cr = nr; cz = nz; cn = nn;
                const int tn = (t + 2 < CHUNK) ? (t + 2) : (CHUNK - 1);
                nr = gxs[(size_t)tn * 384 + dg];
                nz = gxs[(size_t)tn * 384 + 128 + dg];
                nn = gxs[(size_t)tn * 384 + 256 + dg];
            }
            bar_lds();
        }
        if (wav == 4 || wav == 5) hstate[b * 128 + dg] = hown;
        return;
    }

    // ---------- head roles ----------
    int hb = (int)blockIdx.x - ngru;
    if (hb < NH1) {
        const int hc = c - 1;
        if (hc >= 0 && hc < NCHUNK)
            head_layer(zring + (size_t)(hc & 1) * RCH, r1ring + (size_t)(hc & 1) * RCH,
                       h1w, h1b, hb, NH1);
        return;
    }
    hb -= NH1;
    if (hb < NH2) {
        const int hc = c - 2;
        if (hc >= 0 && hc < NCHUNK)
            head_layer(r1ring + (size_t)(hc & 1) * RCH, r2ring + (size_t)(hc & 1) * RCH,
                       h2w, h2b, hb, NH2);
        return;
    }
    hb -= NH2;
    if (hb < NH3) {
        const int hc = c - 3;
        if (hc >= 0 && hc < NCHUNK)
            head3_layer(r2ring + (size_t)(hc & 1) * RCH, h3w, h3b, xc, mc, inv2,
                        lossacc, hb, NH3, hc);
    }
}

__global__ void k_loss(const double* __restrict__ acc, const int* __restrict__ flags,
                       void* __restrict__ out)
{
    double cnt = acc[128];
    double denom = (cnt < 1.0) ? 1.0 : cnt;
    float v = (float)(acc[129] / denom);
    if (flags[0] == 1) ((float*)out)[0] = v;
    else ((unsigned short*)out)[0] = f2bf(v);
}

extern "C" void kernel_launch(void* const* d_in, const int* in_sizes, int n_in,
                              void* d_out, int out_size, void* d_ws, size_t ws_size,
                              hipStream_t stream)
{
    (void)in_sizes; (void)n_in; (void)out_size; (void)ws_size;
    const void* x    = d_in[0];
    const void* mask = d_in[1];

    char* ws = (char*)d_ws;
    unsigned short* xc   = (unsigned short*)(ws + OFF_XC);
    unsigned char*  mc   = (unsigned char*)(ws + OFF_MC);
    float*          wc   = (float*)(ws + OFF_WC);
    double*         acc  = (double*)(ws + OFF_ACC);
    int*            cnt  = (int*)(ws + OFF_ACC + 1056);
    int*            flg  = (int*)(ws + OFF_ACC + 1088);
    float*          inv2 = (float*)(ws + OFF_ACC + 1216);
    unsigned short* h2   = (unsigned short*)(ws + OFF_H2);
    unsigned short* gxr  = (unsigned short*)(ws + OFF_GX);
    unsigned short* zr   = (unsigned short*)(ws + OFF_ZR);
    unsigned short* r1r  = (unsigned short*)(ws + OFF_R1);
    unsigned short* r2r  = (unsigned short*)(ws + OFF_R2);
    float*          hst  = (float*)(ws + OFF_HST);

    const float* stem_w = wc + 0;
    const float* stem_b = wc + 4096;
    const float* conv_w = wc + 4160;
    const float* conv_b = wc + 16448;
    const float* w_ih   = wc + 16512;
    const float* w_hh   = wc + 41088;
    const float* b_ih   = wc + 90240;
    const float* b_hh   = wc + 90624;
    const float* h1_w   = wc + 91008;
    const float* h1_b   = wc + 107392;
    const float* h2_w   = wc + 107520;
    const float* h2_b   = wc + 123904;
    const float* h3_w   = wc + 124032;
    const float* h3_b   = wc + 132224;

    hipMemsetAsync(ws + OFF_ACC, 0, 4096, stream);
    k_probe   <<<256, 256, 0, stream>>>((const unsigned short*)x, (const unsigned char*)mask, cnt);
    k_classify<<<1, 1, 0, stream>>>(cnt, flg);
    k_canon_x <<<8192, 256, 0, stream>>>(x, mask, xc, mc, flg);
    k_canon_w <<<14, 256, 0, stream>>>(d_in[2], d_in[3], d_in[4], d_in[5], d_in[6],
                                       d_in[7], d_in[8], d_in[9], d_in[10], d_in[11],
                                       d_in[12], d_in[13], d_in[14], d_in[15], wc, flg);
    k_std     <<<512, 256, 0, stream>>>(xc, mc, acc);
    k_scale   <<<1, 64, 0, stream>>>(acc, inv2);
    k_stemconv<<<4096, 768, 0, stream>>>(xc, mc, stem_w, stem_b, conv_w, conv_b, h2);
    k_gx0     <<<64, 384, 0, stream>>>(h2, w_ih, b_ih, b_hh, gxr);

    for (int c = 0; c < NCHUNK + 3; ++c) {
        const int ngru = (c < NCHUNK) ? 64 : 0;
        k_mega<<<ngru + NH1 + NH2 + NH3, 768, 0, stream>>>(
            ngru, c, gxr, h2, w_ih, b_ih, w_hh, b_hh,
            zr, r1r, r2r, hst, h1_w, h1_b, h2_w, h2_b, h3_w, h3_b,
            xc, mc, inv2, acc + 129);
    }
    k_loss<<<1, 1, 0, stream>>>(acc, flg, d_out);
}

// Round 6
// 4296.246 us; speedup vs baseline: 1.5578x; 1.5578x over previous
//
#include <hip/hip_runtime.h>
#include <hip/hip_bf16.h>

#define DEV __device__ __forceinline__

namespace {

constexpr int ROWS = 64 * 4096;        // B*T
constexpr int NE   = ROWS * 64;        // B*T*F
constexpr int CHUNK = 512;
constexpr int NCHUNK = 4096 / CHUNK;   // 8
constexpr int NH1 = 48, NH2 = 48, NH3 = 32;

constexpr size_t GXCH = (size_t)64 * CHUNK * 384;   // elems per gx chunk buf
constexpr size_t RCH  = (size_t)64 * CHUNK * 128;   // elems per z/r1/r2 chunk buf

// workspace layout (bytes), total ~185.1 MB
constexpr size_t OFF_XC  = 0;            // bf16 NE          33,554,432
constexpr size_t OFF_MC  = 33554432;     // u8 NE            16,777,216
constexpr size_t OFF_WC  = 50331648;     // fp32 weights
constexpr size_t OFF_ACC = 50862080;     // 4 KB acc/flags
constexpr size_t OFF_H2  = 50866176;     // f16 NE           33,554,432
constexpr size_t OFF_GX  = 84420608;     // f16 2*GXCH       50,331,648
constexpr size_t OFF_ZR  = 134752256;    // f16 2*RCH        16,777,216
constexpr size_t OFF_R1  = 151529472;    // f16 2*RCH
constexpr size_t OFF_R2  = 168306688;    // f16 2*RCH
constexpr size_t OFF_HST = 185083904;    // fp32 64*128

DEV float rlane(float v, int l) {
    return __int_as_float(__builtin_amdgcn_readlane(__float_as_int(v), l));
}
DEV unsigned int rlu(unsigned int v, int l) {
    return (unsigned int)__builtin_amdgcn_readlane((int)v, l);
}
DEV float bf2f(unsigned short u) { return __uint_as_float(((unsigned int)u) << 16); }
DEV unsigned short f2bf(float f) {
    unsigned int u = __float_as_uint(f);
    unsigned int r = (u + 0x7FFFu + ((u >> 16) & 1u)) >> 16;
    return (unsigned short)r;
}
DEV float gelu_f(float v) { return 0.5f * v * (1.0f + erff(v * 0.70710678118654752f)); }
DEV float sigm_f(float x) { return 1.0f / (1.0f + __expf(-x)); }
DEV float tanh_f(float x) { float t = __expf(2.0f * x); return 1.0f - 2.0f / (t + 1.0f); }

typedef _Float16 half2v __attribute__((ext_vector_type(2)));

DEV float dot2(half2v a, half2v b, float c) {
#if __has_builtin(__builtin_amdgcn_fdot2)
    return __builtin_amdgcn_fdot2(a, b, c, false);
#else
    return c + (float)a.x * (float)b.x + (float)a.y * (float)b.y;
#endif
}
DEV unsigned short f2h_bits(float f) {
    return __builtin_bit_cast(unsigned short, (_Float16)f);
}
DEV float h2f_bits(unsigned short u) {
    return (float)__builtin_bit_cast(_Float16, u);
}
DEV half2v u2h2(unsigned int p) { return __builtin_bit_cast(half2v, p); }
// LDS-only barrier: skips the vmcnt(0) drain __syncthreads would emit.
DEV void bar_lds() {
    asm volatile("s_waitcnt lgkmcnt(0)\n\ts_barrier" ::: "memory");
}

} // namespace

// ---------------- dtype probe (memory-safe) ----------------
__global__ __launch_bounds__(256) void k_probe(const unsigned short* __restrict__ xh,
    const unsigned char* __restrict__ mb, int* __restrict__ cnt)
{
    const int g = blockIdx.x * 256 + threadIdx.x;
    int hit = 0;
    for (int i = g; i < (1 << 20); i += (1 << 16)) {
        int tb = (xh[i] >> 8) & 0x7F;
        hit += (tb >= 0x3C && tb <= 0x40) ? 1 : 0;
    }
    int a = 0, b = 0, c = 0, d = 0;
    for (int i = g; i < (1 << 24); i += (1 << 16)) {
        unsigned char v = mb[i];
        int r = i & 3;
        a += (v == 1    && r == 0) ? 1 : 0;
        b += (v == 1    && r != 0) ? 1 : 0;
        c += (v == 0x80 && r == 0) ? 1 : 0;
        d += (v == 0x80 && r == 2) ? 1 : 0;
    }
    __shared__ int sm[256];
    int vals[5] = {hit, a, b, c, d};
#pragma unroll
    for (int k = 0; k < 5; ++k) {
        sm[threadIdx.x] = vals[k];
        __syncthreads();
        for (int s = 128; s > 0; s >>= 1) {
            if (threadIdx.x < s) sm[threadIdx.x] += sm[threadIdx.x + s];
            __syncthreads();
        }
        if (threadIdx.x == 0) atomicAdd(cnt + k, sm[0]);
        __syncthreads();
    }
}

__global__ void k_classify(const int* __restrict__ cnt, int* __restrict__ flags)
{
    flags[0] = (cnt[0] > 786432) ? 0 : 1;
    int fm;
    if (cnt[2] > 0) fm = 0;
    else if (cnt[1] > 0) fm = 1;
    else if (cnt[3] > 0) fm = 2;
    else if (cnt[4] > 0) fm = 3;
    else fm = 0;
    flags[1] = fm;
}

// ---------------- canonicalize x (bf16) + mask (u8) ----------------
__global__ __launch_bounds__(256) void k_canon_x(const void* __restrict__ x,
    const void* __restrict__ mask, unsigned short* __restrict__ xc,
    unsigned char* __restrict__ mc, const int* __restrict__ flags)
{
    const int fF = flags[0], fM = flags[1];
    for (int i = blockIdx.x * 256 + threadIdx.x; i < NE; i += gridDim.x * 256) {
        unsigned short h;
        if (fF == 0) h = ((const unsigned short*)x)[i];
        else         h = f2bf(((const float*)x)[i]);
        xc[i] = h;
        unsigned char m;
        if (fM == 0)      m = (((const unsigned char*)mask)[i]  != 0) ? 1 : 0;
        else if (fM == 1) m = (((const int*)mask)[i]            != 0) ? 1 : 0;
        else if (fM == 2) m = (((const unsigned short*)mask)[i] != 0) ? 1 : 0;
        else              m = (((const unsigned int*)mask)[i]   != 0) ? 1 : 0;
        mc[i] = m;
    }
}

// ---------------- canonicalize weights to fp32 ----------------
__global__ __launch_bounds__(256) void k_canon_w(
    const void* p0, const void* p1, const void* p2, const void* p3,
    const void* p4, const void* p5, const void* p6, const void* p7,
    const void* p8, const void* p9, const void* p10, const void* p11,
    const void* p12, const void* p13, float* __restrict__ wc,
    const int* __restrict__ flags)
{
    const int fF = flags[0];
    const void* p; int off, n;
    switch (blockIdx.x) {
        case 0:  p = p0;  off = 0;      n = 4096;  break;  // stem_w
        case 1:  p = p1;  off = 4096;   n = 64;    break;  // stem_b
        case 2:  p = p2;  off = 4160;   n = 12288; break;  // conv_w
        case 3:  p = p3;  off = 16448;  n = 64;    break;  // conv_b
        case 4:  p = p4;  off = 16512;  n = 24576; break;  // w_ih
        case 5:  p = p5;  off = 41088;  n = 49152; break;  // w_hh
        case 6:  p = p6;  off = 90240;  n = 384;   break;  // b_ih
        case 7:  p = p7;  off = 90624;  n = 384;   break;  // b_hh
        case 8:  p = p8;  off = 91008;  n = 16384; break;  // h1_w
        case 9:  p = p9;  off = 107392; n = 128;   break;  // h1_b
        case 10: p = p10; off = 107520; n = 16384; break;  // h2_w
        case 11: p = p11; off = 123904; n = 128;   break;  // h2_b
        case 12: p = p12; off = 124032; n = 8192;  break;  // h3_w
        default: p = p13; off = 132224; n = 64;    break;  // h3_b
    }
    for (int i = threadIdx.x; i < n; i += 256) {
        float v = (fF == 0) ? bf2f(((const unsigned short*)p)[i]) : ((const float*)p)[i];
        wc[off + i] = v;
    }
}

// ---------------- std over features + mask count ----------------
__global__ __launch_bounds__(256) void k_std(const unsigned short* __restrict__ xc,
    const unsigned char* __restrict__ mc, double* __restrict__ acc)
{
    const int tid = threadIdx.x, f = tid & 63, slot = tid >> 6;
    float s = 0.f, sq = 0.f; int cnt = 0;
    for (int row = blockIdx.x * 4 + slot; row < ROWS; row += gridDim.x * 4) {
        const size_t base = (size_t)row * 64 + f;
        float v = bf2f(xc[base]);
        s += v; sq += v * v;
        cnt += mc[base];
    }
    __shared__ float ls[256], lq[256];
    __shared__ int lc[256];
    ls[tid] = s; lq[tid] = sq; lc[tid] = cnt;
    __syncthreads();
    if (tid < 64) {
        float S = ls[tid] + ls[tid + 64] + ls[tid + 128] + ls[tid + 192];
        float Q = lq[tid] + lq[tid + 64] + lq[tid + 128] + lq[tid + 192];
        atomicAdd(acc + tid, (double)S);
        atomicAdd(acc + 64 + tid, (double)Q);
    }
    if (tid == 0) {
        int tot = 0;
        for (int i = 0; i < 256; ++i) tot += lc[i];
        atomicAdd(acc + 128, (double)tot);
    }
}

__global__ void k_scale(const double* __restrict__ acc, float* __restrict__ inv2)
{
    int f = threadIdx.x;
    const double N = (double)ROWS;
    double sum = acc[f], sq = acc[64 + f];
    double var = (sq - sum * sum / N) / (N - 1.0);
    double sd = sqrt(var) + 1e-8;
    inv2[f] = (float)(1.0 / (sd * sd));
}

// ---------------- fused stem + conv (halo strip in LDS), h2 f16 out --------
__global__ __launch_bounds__(768) void k_stemconv(const unsigned short* __restrict__ xc,
    const unsigned char* __restrict__ mc, const float* __restrict__ sw,
    const float* __restrict__ sb, const float* __restrict__ cw,
    const float* __restrict__ cb, unsigned short* __restrict__ h2)
{
    __shared__ float h1s[66][64];
    __shared__ float parts[3][4][64];
    const int tid = threadIdx.x, lane = tid & 63, wav = tid >> 6;
    const int b = blockIdx.x >> 6, strip = blockIdx.x & 63, t0 = strip * 64;

    float wv[64];
#pragma unroll
    for (int d = 0; d < 64; ++d) wv[d] = sw[d * 64 + lane];
    const float sbias = sb[lane];
    for (int rr = wav; rr < 66; rr += 12) {
        const int tr = t0 + rr - 1;
        float val = 0.f;
        if (tr >= 0 && tr < 4096) {
            const size_t base = ((size_t)b * 4096 + tr) * 64;
            float xv = bf2f(xc[base + lane]);
            if (mc[base + lane]) xv = 0.f;
            float a0 = 0.f, a1 = 0.f, a2 = 0.f, a3 = 0.f;
#pragma unroll
            for (int d = 0; d < 64; d += 4) {
                a0 += rlane(xv, d    ) * wv[d    ];
                a1 += rlane(xv, d + 1) * wv[d + 1];
                a2 += rlane(xv, d + 2) * wv[d + 2];
                a3 += rlane(xv, d + 3) * wv[d + 3];
            }
            val = gelu_f(((a0 + a1) + (a2 + a3)) + sbias);
        }
        h1s[rr][lane] = val;
    }
    __syncthreads();

    const int k = wav >> 2, j = wav & 3;
    float cwv[64];
#pragma unroll
    for (int i = 0; i < 64; ++i) cwv[i] = cw[lane * 192 + i * 3 + k];
    const float cbias = cb[lane];
    for (int it = 0; it < 16; ++it) {
        const int row = it * 4 + j;
        float hv = h1s[row + k][lane];
        float a0 = 0.f, a1 = 0.f, a2 = 0.f, a3 = 0.f;
#pragma unroll
        for (int i = 0; i < 64; i += 4) {
            a0 += rlane(hv, i    ) * cwv[i    ];
            a1 += rlane(hv, i + 1) * cwv[i + 1];
            a2 += rlane(hv, i + 2) * cwv[i + 2];
            a3 += rlane(hv, i + 3) * cwv[i + 3];
        }
        parts[k][j][lane] = (a0 + a1) + (a2 + a3);
        __syncthreads();
        if (tid < 256) {
            const int jj = tid >> 6;
            const int row2 = it * 4 + jj;
            float v = parts[0][jj][lane] + parts[1][jj][lane] + parts[2][jj][lane] + cbias;
            h2[((size_t)b * 4096 + t0 + row2) * 64 + lane] = f2h_bits(gelu_f(v));
        }
        __syncthreads();
    }
}

// ---------------- gx for chunk 0 (standalone) ----------------
__global__ __launch_bounds__(384) void k_gx0(const unsigned short* __restrict__ h2,
    const float* __restrict__ wih, const float* __restrict__ bih,
    const float* __restrict__ bhh, unsigned short* __restrict__ gx0)
{
    const int tid = threadIdx.x, lane = tid & 63, wav = tid >> 6; // 6 waves
    const int col = wav * 64 + lane;
    half2v wg[32];
#pragma unroll
    for (int i = 0; i < 32; ++i)
        wg[i] = half2v{(_Float16)wih[(size_t)col * 64 + 2 * i],
                       (_Float16)wih[(size_t)col * 64 + 2 * i + 1]};
    const float gb = bih[col] + (col < 256 ? bhh[col] : 0.f);
    const unsigned int* h232 = (const unsigned int*)h2;
    const int b = blockIdx.x;
    const size_t hb = (size_t)b * 4096 * 32;
    unsigned int hw = h232[hb + (lane & 31)];
    for (int t = 0; t < CHUNK; ++t) {
        unsigned int hwn = (t + 1 < CHUNK) ? h232[hb + (size_t)(t + 1) * 32 + (lane & 31)] : 0u;
        float s = 0.f;
#pragma unroll
        for (int i = 0; i < 32; ++i)
            s = dot2(u2h2(rlu(hw, i)), wg[i], s);
        gx0[((size_t)b * CHUNK + t) * 384 + col] = f2h_bits(s + gb);
        hw = hwn;
    }
}

// ---------------- head helpers (512 threads = 8 waves) ----------------
DEV void head_layer(const unsigned short* __restrict__ in,
                    unsigned short* __restrict__ out,
                    const float* __restrict__ w, const float* __restrict__ bias,
                    int hb, int nb)
{
    const int tid = threadIdx.x, lane = tid & 63, wav = tid >> 6;
    const int tm = wav >> 1, cs = wav & 1;            // 4 row-slots x 2 col-halves
    const int col = cs * 64 + lane;
    half2v wv[64];
#pragma unroll
    for (int i = 0; i < 64; ++i)
        wv[i] = half2v{(_Float16)w[(size_t)(2 * i) * 128 + col],
                       (_Float16)w[(size_t)(2 * i + 1) * 128 + col]};
    const float bb = bias[col];
    for (int r = hb * 4 + tm; r < 64 * CHUNK; r += nb * 4) {
        const unsigned int* ir = (const unsigned int*)(in + (size_t)r * 128);
        unsigned int zw = ir[lane];       // pairs (z[2lane], z[2lane+1])
        float a0 = 0.f, a1 = 0.f;
#pragma unroll
        for (int i = 0; i < 64; i += 2) {
            a0 = dot2(u2h2(rlu(zw, i)),     wv[i],     a0);
            a1 = dot2(u2h2(rlu(zw, i + 1)), wv[i + 1], a1);
        }
        out[(size_t)r * 128 + col] = f2h_bits(gelu_f(a0 + a1 + bb));
    }
}

DEV void head3_layer(const unsigned short* __restrict__ in,
                     const float* __restrict__ w, const float* __restrict__ bias,
                     const unsigned short* __restrict__ xc,
                     const unsigned char* __restrict__ mc,
                     const float* __restrict__ inv2, double* __restrict__ lossacc,
                     int hb, int nb, int hc)
{
    const int tid = threadIdx.x, lane = tid & 63, wav = tid >> 6;
    half2v wv[64];
#pragma unroll
    for (int i = 0; i < 64; ++i)
        wv[i] = half2v{(_Float16)w[(size_t)(2 * i) * 64 + lane],
                       (_Float16)w[(size_t)(2 * i + 1) * 64 + lane]};
    const float bb = bias[lane];
    const float iv = inv2[lane];
    float accf = 0.f; double acc = 0.0; int spill = 0;
    for (int r = hb * 8 + wav; r < 64 * CHUNK; r += nb * 8) {
        const unsigned int* ir = (const unsigned int*)(in + (size_t)r * 128);
        unsigned int zw = ir[lane];
        float a0 = 0.f, a1 = 0.f;
#pragma unroll
        for (int i = 0; i < 64; i += 2) {
            a0 = dot2(u2h2(rlu(zw, i)),     wv[i],     a0);
            a1 = dot2(u2h2(rlu(zw, i + 1)), wv[i + 1], a1);
        }
        float xr = a0 + a1 + bb;
        const int bidx = r >> 9, tl = r & (CHUNK - 1);
        const int t = hc * CHUNK + tl;
        const size_t xb = ((size_t)bidx * 4096 + t) * 64 + lane;
        float dd = xr - bf2f(xc[xb]);
        accf += mc[xb] ? dd * dd * iv : 0.f;
        if (++spill == 64) { acc += (double)accf; accf = 0.f; spill = 0; }
    }
    acc += (double)accf;
    __shared__ double red[512];
    red[tid] = acc;
    __syncthreads();
    for (int s = 256; s > 0; s >>= 1) {
        if (tid < s) red[tid] += red[tid + s];
        __syncthreads();
    }
    if (tid == 0) atomicAdd(lossacc, red[0]);
}

// ---------------- pipelined chunk launch ----------------
// blocks [0,64): GRU chunk c (R4-proven 8-wave structure, 2 lgkm barriers/step)
// blocks [64,128): gx for chunk c+1 (f16 dot2, 6 active waves)
// blocks [128,176): head1(c-1); [176,224): head2(c-2); [224,256): head3(c-3)
__global__ __launch_bounds__(512) void k_pipe(int c,
    unsigned short* __restrict__ gxring, const unsigned short* __restrict__ h2,
    const float* __restrict__ wih, const float* __restrict__ bih,
    const float* __restrict__ whh, const float* __restrict__ bhh,
    unsigned short* __restrict__ zring, unsigned short* __restrict__ r1ring,
    unsigned short* __restrict__ r2ring, float* __restrict__ hstate,
    const float* __restrict__ h1w, const float* __restrict__ h1b,
    const float* __restrict__ h2w, const float* __restrict__ h2b,
    const float* __restrict__ h3w, const float* __restrict__ h3b,
    const unsigned short* __restrict__ xc, const unsigned char* __restrict__ mc,
    const float* __restrict__ inv2, double* __restrict__ lossacc)
{
    const int tid = threadIdx.x, lane = tid & 63, wav = tid >> 6;

    if (blockIdx.x < 64) {
        // ---------------- GRU role (R4 k_fused structure) ----------------
        if (c >= NCHUNK) return;
        __shared__ float part[4][3][130];
        __shared__ unsigned int hpk[64];   // h as packed f16 pairs
        const int b = blockIdx.x;
        const int half = wav & 1, ksw = wav >> 1;
        const int d = half * 64 + lane;
        const int kb = __builtin_amdgcn_readfirstlane(ksw * 16);
        const unsigned short* gxb = gxring + (size_t)(c & 1) * GXCH + (size_t)b * CHUNK * 384;
        unsigned short* zc = zring + (size_t)(c & 1) * RCH + (size_t)b * CHUNK * 128;

        half2v wr[16], wz[16], wn[16];
#pragma unroll
        for (int i = 0; i < 16; ++i) {
            const int k0 = ksw * 32 + 2 * i;
            wr[i] = half2v{(_Float16)whh[(size_t)d * 128 + k0],
                           (_Float16)whh[(size_t)d * 128 + k0 + 1]};
            wz[i] = half2v{(_Float16)whh[(size_t)(128 + d) * 128 + k0],
                           (_Float16)whh[(size_t)(128 + d) * 128 + k0 + 1]};
            wn[i] = half2v{(_Float16)whh[(size_t)(256 + d) * 128 + k0],
                           (_Float16)whh[(size_t)(256 + d) * 128 + k0 + 1]};
        }
        const float bhn = bhh[256 + d];

        float hown = 0.0f;
        if (c > 0 && tid < 128) hown = hstate[b * 128 + tid];
        if (tid < 64) {
            float h0 = 0.f, h1v = 0.f;
            if (c > 0) {
                h0  = hstate[b * 128 + 2 * lane];
                h1v = hstate[b * 128 + 2 * lane + 1];
            }
            hpk[lane] = (unsigned int)f2h_bits(h0) | ((unsigned int)f2h_bits(h1v) << 16);
        }
        unsigned short cur[24], nxt[24];
        if (tid < 128) {
#pragma unroll
            for (int ti = 0; ti < 8; ++ti)
#pragma unroll
                for (int g3 = 0; g3 < 3; ++g3) {
                    cur[ti * 3 + g3] = gxb[(size_t)ti * 384 + g3 * 128 + tid];
                    nxt[ti * 3 + g3] = gxb[(size_t)(8 + ti) * 384 + g3 * 128 + tid];
                }
        }
        __syncthreads();

        for (int tb = 0; tb < CHUNK / 8; ++tb) {
#pragma unroll
            for (int ti = 0; ti < 8; ++ti) {
                const unsigned int hw = hpk[lane];
                float sr = 0.f, sz = 0.f, sn = 0.f;
#pragma unroll
                for (int i = 0; i < 16; ++i) {
                    const half2v hp = u2h2(rlu(hw, kb + i));
                    sr = dot2(hp, wr[i], sr);
                    sz = dot2(hp, wz[i], sz);
                    sn = dot2(hp, wn[i], sn);
                }
                part[ksw][0][d] = sr;
                part[ksw][1][d] = sz;
                part[ksw][2][d] = sn;
                bar_lds();
                if (tid < 128) {
                    const float gr  = part[0][0][tid] + part[1][0][tid] + part[2][0][tid]
                                    + part[3][0][tid] + h2f_bits(cur[ti * 3 + 0]);
                    const float gz  = part[0][1][tid] + part[1][1][tid] + part[2][1][tid]
                                    + part[3][1][tid] + h2f_bits(cur[ti * 3 + 1]);
                    const float gnh = part[0][2][tid] + part[1][2][tid] + part[2][2][tid]
                                    + part[3][2][tid] + bhn;
                    const float r  = sigm_f(gr);
                    const float zg = sigm_f(gz);
                    const float n  = tanh_f(h2f_bits(cur[ti * 3 + 2]) + r * gnh);
                    hown = n + zg * (hown - n);
                    ((unsigned short*)hpk)[tid] = f2h_bits(hown);
                    zc[(size_t)(tb * 8 + ti) * 128 + tid] = f2h_bits(hown);
                }
                bar_lds();
            }
            if (tid < 128) {
#pragma unroll
                for (int j = 0; j < 24; ++j) cur[j] = nxt[j];
                const int tnb = (tb + 2 <= CHUNK / 8 - 1) ? (tb + 2) * 8 : (CHUNK - 8);
#pragma unroll
                for (int ti = 0; ti < 8; ++ti)
#pragma unroll
                    for (int g3 = 0; g3 < 3; ++g3)
                        nxt[ti * 3 + g3] = gxb[(size_t)(tnb + ti) * 384 + g3 * 128 + tid];
            }
        }
        if (tid < 128) hstate[b * 128 + tid] = hown;
        return;
    }

    if (blockIdx.x < 128) {
        // ---------------- gx role for chunk c+1 ----------------
        if (c + 1 >= NCHUNK || wav >= 6) return;
        const int b = blockIdx.x - 64;
        unsigned short* gxd = gxring + (size_t)((c + 1) & 1) * GXCH + (size_t)b * CHUNK * 384;
        const int col = wav * 64 + lane;
        half2v wg[32];
#pragma unroll
        for (int i = 0; i < 32; ++i)
            wg[i] = half2v{(_Float16)wih[(size_t)col * 64 + 2 * i],
                           (_Float16)wih[(size_t)col * 64 + 2 * i + 1]};
        const float gb = bih[col] + (col < 256 ? bhh[col] : 0.f);
        const unsigned int* h232 = (const unsigned int*)h2;
        const size_t hb = ((size_t)b * 4096 + (size_t)(c + 1) * CHUNK) * 32;
        unsigned int hw = h232[hb + (lane & 31)];
        for (int t = 0; t < CHUNK; ++t) {
            unsigned int hwn = (t + 1 < CHUNK) ? h232[hb + (size_t)(t + 1) * 32 + (lane & 31)] : 0u;
            float s = 0.f;
#pragma unroll
            for (int i = 0; i < 32; ++i)
                s = dot2(u2h2(rlu(hw, i)), wg[i], s);
            gxd[(size_t)t * 384 + col] = f2h_bits(s + gb);
            hw = hwn;
        }
        return;
    }

    // ---------------- head roles ----------------
    int hb = (int)blockIdx.x - 128;
    if (hb < NH1) {
        const int hc = c - 1;
        if (hc >= 0 && hc < NCHUNK)
            head_layer(zring + (size_t)(hc & 1) * RCH, r1ring + (size_t)(hc & 1) * RCH,
                       h1w, h1b, hb, NH1);
        return;
    }
    hb -= NH1;
    if (hb < NH2) {
        const int hc = c - 2;
        if (hc >= 0 && hc < NCHUNK)
            head_layer(r1ring + (size_t)(hc & 1) * RCH, r2ring + (size_t)(hc & 1) * RCH,
                       h2w, h2b, hb, NH2);
        return;
    }
    hb -= NH2;
    {
        const int hc = c - 3;
        if (hc >= 0 && hc < NCHUNK)
            head3_layer(r2ring + (size_t)(hc & 1) * RCH, h3w, h3b, xc, mc, inv2,
                        lossacc, hb, NH3, hc);
    }
}

__global__ void k_loss(const double* __restrict__ acc, const int* __restrict__ flags,
                       void* __restrict__ out)
{
    double cnt = acc[128];
    double denom = (cnt < 1.0) ? 1.0 : cnt;
    float v = (float)(acc[129] / denom);
    if (flags[0] == 1) ((float*)out)[0] = v;
    else ((unsigned short*)out)[0] = f2bf(v);
}

extern "C" void kernel_launch(void* const* d_in, const int* in_sizes, int n_in,
                              void* d_out, int out_size, void* d_ws, size_t ws_size,
                              hipStream_t stream)
{
    (void)in_sizes; (void)n_in; (void)out_size; (void)ws_size;
    const void* x    = d_in[0];
    const void* mask = d_in[1];

    char* ws = (char*)d_ws;
    unsigned short* xc   = (unsigned short*)(ws + OFF_XC);
    unsigned char*  mc   = (unsigned char*)(ws + OFF_MC);
    float*          wc   = (float*)(ws + OFF_WC);
    double*         acc  = (double*)(ws + OFF_ACC);
    int*            cnt  = (int*)(ws + OFF_ACC + 1056);
    int*            flg  = (int*)(ws + OFF_ACC + 1088);
    float*          inv2 = (float*)(ws + OFF_ACC + 1216);
    unsigned short* h2   = (unsigned short*)(ws + OFF_H2);
    unsigned short* gxr  = (unsigned short*)(ws + OFF_GX);
    unsigned short* zr   = (unsigned short*)(ws + OFF_ZR);
    unsigned short* r1r  = (unsigned short*)(ws + OFF_R1);
    unsigned short* r2r  = (unsigned short*)(ws + OFF_R2);
    float*          hst  = (float*)(ws + OFF_HST);

    const float* stem_w = wc + 0;
    const float* stem_b = wc + 4096;
    const float* conv_w = wc + 4160;
    const float* conv_b = wc + 16448;
    const float* w_ih   = wc + 16512;
    const float* w_hh   = wc + 41088;
    const float* b_ih   = wc + 90240;
    const float* b_hh   = wc + 90624;
    const float* h1_w   = wc + 91008;
    const float* h1_b   = wc + 107392;
    const float* h2_w   = wc + 107520;
    const float* h2_b   = wc + 123904;
    const float* h3_w   = wc + 124032;
    const float* h3_b   = wc + 132224;

    hipMemsetAsync(ws + OFF_ACC, 0, 4096, stream);
    k_probe   <<<256, 256, 0, stream>>>((const unsigned short*)x, (const unsigned char*)mask, cnt);
    k_classify<<<1, 1, 0, stream>>>(cnt, flg);
    k_canon_x <<<8192, 256, 0, stream>>>(x, mask, xc, mc, flg);
    k_canon_w <<<14, 256, 0, stream>>>(d_in[2], d_in[3], d_in[4], d_in[5], d_in[6],
                                       d_in[7], d_in[8], d_in[9], d_in[10], d_in[11],
                                       d_in[12], d_in[13], d_in[14], d_in[15], wc, flg);
    k_std     <<<512, 256, 0, stream>>>(xc, mc, acc);
    k_scale   <<<1, 64, 0, stream>>>(acc, inv2);
    k_stemconv<<<4096, 768, 0, stream>>>(xc, mc, stem_w, stem_b, conv_w, conv_b, h2);
    k_gx0     <<<64, 384, 0, stream>>>(h2, w_ih, b_ih, b_hh, gxr);

    for (int c = 0; c < NCHUNK + 3; ++c) {
        k_pipe<<<256, 512, 0, stream>>>(
            c, gxr, h2, w_ih, b_ih, w_hh, b_hh,
            zr, r1r, r2r, hst, h1_w, h1_b, h2_w, h2_b, h3_w, h3_b,
            xc, mc, inv2, acc + 129);
    }
    k_loss<<<1, 1, 0, stream>>>(acc, flg, d_out);
}